// Round 5
// baseline (406.795 us; speedup 1.0000x reference)
//
#include <hip/hip_runtime.h>

// ---------------------------------------------------------------------------
// Fused MHA block on MI355X (gfx950). fp16 MFMA, fp32 accum.
// Round-5: GEMM engine switched 16x16x32 -> 32x32x16 (half the MFMA issue
// count, higher ceiling 2495 vs 2075 TF). Wave tile 64x64 = 2x2 of 32x32.
// C/D layout (m74/m101-verified): col=lane&31, row=(reg&3)+8*(reg>>2)+4*(lane>>5).
// A/B layout: m|n = lane&31, k = (lane>>5)*8 + j.
// Flash kept on the validated 16x16 path (port next round if engine checks out).
// wo-GEMM back to 128x128 (BN=64 was neutral; per-block intensity wins).
// ---------------------------------------------------------------------------

typedef _Float16 half8 __attribute__((ext_vector_type(8)));
typedef float floatx4 __attribute__((ext_vector_type(4)));
typedef float floatx16 __attribute__((ext_vector_type(16)));

__device__ __forceinline__ void async16(const void* g, void* l) {
  __builtin_amdgcn_global_load_lds((__attribute__((address_space(1))) void*)(g),
                                   (__attribute__((address_space(3))) void*)(l),
                                   16, 0, 0);
}

// ---- fp32 -> fp16 convert (x) ----------------------------------------------
__global__ void cvt_f32_f16(const float* __restrict__ src, _Float16* __restrict__ dst,
                            int n4) {
  int i = blockIdx.x * blockDim.x + threadIdx.x;
  if (i >= n4) return;
  float4 v = reinterpret_cast<const float4*>(src)[i];
  union { _Float16 h[4]; short4 s; } u;
  u.h[0] = (_Float16)v.x; u.h[1] = (_Float16)v.y;
  u.h[2] = (_Float16)v.z; u.h[3] = (_Float16)v.w;
  reinterpret_cast<short4*>(dst)[i] = u.s;
}

// ---- all 4 weights in one dispatch; wq gets scale*log2e folded in ----------
__global__ void cvt_w4(const float* __restrict__ w0, const float* __restrict__ w1,
                       const float* __restrict__ w2, const float* __restrict__ w3,
                       _Float16* __restrict__ dst, float scale0) {
  int i = blockIdx.x * blockDim.x + threadIdx.x;   // 4 * 2^20 float4 groups
  int m = i >> 20, j = i & ((1 << 20) - 1);
  const float* src = (m == 0) ? w0 : (m == 1) ? w1 : (m == 2) ? w2 : w3;
  float sc = (m == 0) ? scale0 : 1.0f;
  float4 v = reinterpret_cast<const float4*>(src)[j];
  union { _Float16 h[4]; short4 s; } u;
  u.h[0] = (_Float16)(v.x * sc); u.h[1] = (_Float16)(v.y * sc);
  u.h[2] = (_Float16)(v.z * sc); u.h[3] = (_Float16)(v.w * sc);
  reinterpret_cast<short4*>(dst)[i] = u.s;
}

// ---- NT GEMM, 32x32x16 engine: C[m][n] = sum_k A[m][k]*Bw[n][k] ------------
// 128x128 tile, BK=64, 4 waves 2x2, wave tile 64x64 = 2x2 MFMA tiles of 32x32.
// OUT_MODE 0: fused QKV epilogue (n<4096 -> Q/K row-major fp16 into Cv;
//             n>=4096 -> V per-batch transposed [b][d][s] into Cv2)
// OUT_MODE 2: fp32 row-major (final output), ld=2048
template <int OUT_MODE>
__global__ __launch_bounds__(256)
void gemm_nt32(const _Float16* __restrict__ A, const _Float16* __restrict__ Bw,
               void* __restrict__ Cv, void* __restrict__ Cv2, int K) {
  __shared__ _Float16 As[128 * 64];
  __shared__ _Float16 Bs[128 * 64];
  const int tid = threadIdx.x;
  const int wave = tid >> 6, lane = tid & 63;
  const int wm = wave >> 1, wn = wave & 1;
  const int l31 = lane & 31, l5 = lane >> 5;
  const int bm = blockIdx.y, bn = blockIdx.x;

  floatx16 acc[2][2] = {};

  for (int k0 = 0; k0 < K; k0 += 64) {
    __syncthreads();
#pragma unroll
    for (int i = 0; i < 4; ++i) {
      int c = i * 256 + tid;
      int row = c >> 3, cc = c & 7;
      int g = cc ^ (row & 7);                       // xor-swizzle global chunk
      async16(A + (size_t)(bm * 128 + row) * K + k0 + g * 8, &As[c * 8]);
      async16(Bw + (size_t)(bn * 128 + row) * K + k0 + g * 8, &Bs[c * 8]);
    }
    __syncthreads();
#pragma unroll
    for (int ks = 0; ks < 4; ++ks) {                // K=16 per MFMA step
      half8 af[2], bf[2];
      int ch = (ks * 2 + l5) ^ (l31 & 7);           // read swizzle (rows %8 == l31%8)
#pragma unroll
      for (int t = 0; t < 2; ++t) {
        af[t] = *reinterpret_cast<const half8*>(&As[(wm * 64 + t * 32 + l31) * 64 + ch * 8]);
        bf[t] = *reinterpret_cast<const half8*>(&Bs[(wn * 64 + t * 32 + l31) * 64 + ch * 8]);
      }
#pragma unroll
      for (int mt = 0; mt < 2; ++mt)
#pragma unroll
        for (int nt = 0; nt < 2; ++nt)
          acc[mt][nt] = __builtin_amdgcn_mfma_f32_32x32x16_f16(af[mt], bf[nt], acc[mt][nt], 0, 0, 0);
    }
  }

  const int rbase = bm * 128 + wm * 64;
  const int cbase = bn * 128 + wn * 64;
  if constexpr (OUT_MODE == 0) {
    if (cbase < 4096) {           // Q or K: row-major fp16, ld 2048
      _Float16* C = (_Float16*)Cv + (size_t)(cbase >> 11) * (4096ull * 2048);
#pragma unroll
      for (int mt = 0; mt < 2; ++mt)
#pragma unroll
        for (int nt = 0; nt < 2; ++nt) {
          int cg = (cbase + nt * 32 + l31) & 2047;
#pragma unroll
          for (int r = 0; r < 16; ++r) {
            int row = rbase + mt * 32 + (r & 3) + 8 * (r >> 2) + 4 * l5;
            C[(size_t)row * 2048 + cg] = (_Float16)acc[mt][nt][r];
          }
        }
    } else {                      // V: per-batch transposed [b][d][s]
      _Float16* C = (_Float16*)Cv2;
#pragma unroll
      for (int mt = 0; mt < 2; ++mt)
#pragma unroll
        for (int nt = 0; nt < 2; ++nt) {
          int d = cbase + nt * 32 + l31 - 4096;
#pragma unroll
          for (int g = 0; g < 4; ++g) {             // r = g*4 + rr -> 4 consecutive s
            int s0 = rbase + mt * 32 + 8 * g + 4 * l5;
            size_t base = (size_t)(s0 >> 11) * (2048ull * 2048) + (size_t)d * 2048 + (s0 & 2047);
            union { _Float16 h[4]; short4 s; } u;
#pragma unroll
            for (int rr = 0; rr < 4; ++rr) u.h[rr] = (_Float16)acc[mt][nt][g * 4 + rr];
            *reinterpret_cast<short4*>(C + base) = u.s;
          }
        }
    }
  } else {
    float* C = (float*)Cv;
#pragma unroll
    for (int mt = 0; mt < 2; ++mt)
#pragma unroll
      for (int nt = 0; nt < 2; ++nt) {
        int cg = cbase + nt * 32 + l31;
#pragma unroll
        for (int r = 0; r < 16; ++r) {
          int row = rbase + mt * 32 + (r & 3) + 8 * (r >> 2) + 4 * l5;
          C[(size_t)row * 2048 + cg] = acc[mt][nt][r];
        }
      }
  }
}

// ---- Flash attention (unchanged from round 4 -- validated) ------------------
// grid = (16 q-tiles of 128, 32 b*h); block = 256 (4 waves x 32 q rows).
// Fixed-max softmax: p = 2^(s'), s' = q.k with 1/sqrt(128)*log2(e) pre-folded.
__global__ __launch_bounds__(256, 2)
void flash_attn(const _Float16* __restrict__ Q, const _Float16* __restrict__ Kg,
                const _Float16* __restrict__ Vt, _Float16* __restrict__ O) {
  __shared__ _Float16 Ks[64 * 128];   // [key][hd], 16-chunk xor swizzle
  __shared__ _Float16 Vs[128 * 64];   // [d][s],    8-chunk xor swizzle
  __shared__ _Float16 Ps[128 * 64];   // [q][key],  8-chunk xor swizzle
  const int tid = threadIdx.x, wave = tid >> 6, lane = tid & 63;
  const int l15 = lane & 15, l4 = lane >> 4;
  const int bh = blockIdx.y, b = bh >> 4, h = bh & 15;
  const int q0 = blockIdx.x * 128;

  const _Float16* Qp = Q + ((size_t)(b * 2048 + q0 + wave * 32)) * 2048 + h * 128;
  const _Float16* Kp = Kg + (size_t)b * 2048 * 2048 + h * 128;
  const _Float16* Vp = Vt + (size_t)b * 2048 * 2048 + (size_t)(h * 128) * 2048;

  half8 qf[2][4];
#pragma unroll
  for (int mt = 0; mt < 2; ++mt)
#pragma unroll
    for (int ks = 0; ks < 4; ++ks)
      qf[mt][ks] = *reinterpret_cast<const half8*>(
          Qp + (size_t)(mt * 16 + l15) * 2048 + ks * 32 + l4 * 8);

  floatx4 oacc[2][8] = {};
  float lsum[2][4] = {};

  for (int k0 = 0; k0 < 2048; k0 += 64) {
    __syncthreads();
#pragma unroll
    for (int i = 0; i < 4; ++i) {                 // K: 64 rows x 16 chunks
      int c = i * 256 + tid;
      int row = c >> 4, cc = c & 15;
      int g = cc ^ (row & 15);
      async16(Kp + (size_t)(k0 + row) * 2048 + g * 8, &Ks[c * 8]);
    }
#pragma unroll
    for (int i = 0; i < 4; ++i) {                 // V: 128 rows x 8 chunks
      int c = i * 256 + tid;
      int row = c >> 3, cc = c & 7;
      int g = cc ^ (row & 7);
      async16(Vp + (size_t)row * 2048 + k0 + g * 8, &Vs[c * 8]);
    }
    __syncthreads();

    // ---- S = Q K^T ----
    floatx4 sacc[2][4] = {};
#pragma unroll
    for (int ks = 0; ks < 4; ++ks) {
      half8 bf[4];
#pragma unroll
      for (int nt = 0; nt < 4; ++nt) {
        int row = nt * 16 + l15;
        int ch = (ks * 4 + l4) ^ l15;             // row & 15 == l15
        bf[nt] = *reinterpret_cast<const half8*>(&Ks[row * 128 + ch * 8]);
      }
#pragma unroll
      for (int mt = 0; mt < 2; ++mt)
#pragma unroll
        for (int nt = 0; nt < 4; ++nt)
          sacc[mt][nt] = __builtin_amdgcn_mfma_f32_16x16x32_f16(qf[mt][ks], bf[nt], sacc[mt][nt], 0, 0, 0);
    }

    // ---- p = 2^s, accumulate per-lane row partial sums, store P to LDS ----
#pragma unroll
    for (int mt = 0; mt < 2; ++mt)
#pragma unroll
      for (int nt = 0; nt < 4; ++nt)
#pragma unroll
        for (int r = 0; r < 4; ++r) {
          float p = exp2f(sacc[mt][nt][r]);
          lsum[mt][r] += p;
          int rl = l4 * 4 + r;                    // row within 16x16 tile
          int ch = (nt * 2 + (l15 >> 3)) ^ (rl & 7);
          Ps[(wave * 32 + mt * 16 + rl) * 64 + ch * 8 + (l15 & 7)] = (_Float16)p;
        }

    __builtin_amdgcn_s_waitcnt(0xC07F);  // lgkmcnt(0): own-wave ds_write->ds_read

    // ---- O += P V  (V stored (d,s): NT GEMM) ----
#pragma unroll
    for (int ks2 = 0; ks2 < 2; ++ks2) {
      half8 pf[2];
#pragma unroll
      for (int mt = 0; mt < 2; ++mt)
        pf[mt] = *reinterpret_cast<const half8*>(
            &Ps[(wave * 32 + mt * 16 + l15) * 64 + (((ks2 * 4 + l4) ^ (l15 & 7)) * 8)]);
#pragma unroll
      for (int nt2 = 0; nt2 < 8; ++nt2) {
        int row = nt2 * 16 + l15;
        int ch = (ks2 * 4 + l4) ^ (row & 7);
        half8 vf = *reinterpret_cast<const half8*>(&Vs[row * 64 + ch * 8]);
#pragma unroll
        for (int mt = 0; mt < 2; ++mt)
          oacc[mt][nt2] = __builtin_amdgcn_mfma_f32_16x16x32_f16(pf[mt], vf, oacc[mt][nt2], 0, 0, 0);
      }
    }
  }

  // row sums: reduce across the 16 lanes holding different key-columns
#pragma unroll
  for (int mt = 0; mt < 2; ++mt)
#pragma unroll
    for (int r = 0; r < 4; ++r) {
#pragma unroll
      for (int off = 1; off < 16; off <<= 1) lsum[mt][r] += __shfl_xor(lsum[mt][r], off);
    }

  _Float16* Op = O + ((size_t)(b * 2048 + q0 + wave * 32)) * 2048 + h * 128;
#pragma unroll
  for (int mt = 0; mt < 2; ++mt)
#pragma unroll
    for (int r = 0; r < 4; ++r) {
      float inv = 1.0f / lsum[mt][r];
#pragma unroll
      for (int nt2 = 0; nt2 < 8; ++nt2) {
        int row = mt * 16 + l4 * 4 + r;
        int col = nt2 * 16 + l15;
        Op[(size_t)row * 2048 + col] = (_Float16)(oacc[mt][nt2][r] * inv);
      }
    }
}

// ---------------------------------------------------------------------------
extern "C" void kernel_launch(void* const* d_in, const int* in_sizes, int n_in,
                              void* d_out, int out_size, void* d_ws, size_t ws_size,
                              hipStream_t stream) {
  const float* x = (const float*)d_in[0];
  const float* wq = (const float*)d_in[1];
  const float* wk = (const float*)d_in[2];
  const float* wv = (const float*)d_in[3];
  const float* wo = (const float*)d_in[4];
  float* out = (float*)d_out;

  const size_t XN = (size_t)4096 * 2048;
  const size_t WN = (size_t)2048 * 2048;
  _Float16* xh = (_Float16*)d_ws;
  _Float16* qh = xh + XN;          // Q then K contiguous (row-major, ld 2048)
  _Float16* vth = xh + 3 * XN;     // per-batch transposed V
  _Float16* oh = xh + 4 * XN;
  _Float16* wqh = xh + 5 * XN;     // wq,wk,wv,wo contiguous -> fused QKV GEMM

  // 1/sqrt(128) * log2(e): softmax via exp2, scale folded into w_q
  const float SM_SCALE = 0.08838834764831845f * 1.4426950408889634f;

  cvt_f32_f16<<<dim3((int)(XN / 4 / 256)), 256, 0, stream>>>(x, xh, (int)(XN / 4));
  cvt_w4<<<dim3((int)(4 * WN / 4 / 256)), 256, 0, stream>>>(wq, wk, wv, wo, wqh, SM_SCALE);

  gemm_nt32<0><<<dim3(48, 32), 256, 0, stream>>>(xh, wqh, qh, vth, 2048);
  flash_attn<<<dim3(16, 32), 256, 0, stream>>>(qh, qh + XN, vth, oh);
  gemm_nt32<2><<<dim3(16, 32), 256, 0, stream>>>(oh, wqh + 3 * WN, out, nullptr, 2048);
}